// Round 8
// baseline (156.681 us; speedup 1.0000x reference)
//
#include <hip/hip_runtime.h>

// Path signature, depth 4: B=32, L=1024, d=8, fp32.
// Levels: S1(8) S2(64) S3(512) S4(4096); sig stride 4680 floats.
//
// R8: one fused kernel, 256 blocks x 256 threads, 2 grid barriers.
//  Phase A: 1024 waves, one chunk (32 incs) each; block stages its 129 path
//    rows into LDS first (one coalesced HBM latency instead of 32 serial).
//  Phase B: blocks 0..127, one (batch,group) per block; the 8 B-sigs are
//    staged into double-buffered padded LDS tiles (coalesced float4, next-sig
//    loads issued before the current fold) and folded k-sliced from LDS.
//  Phase C: blocks 0..31, same staged-fold over the 4 partials -> d_out.
// Lessons: (R2) never unroll fold loops; (R3) reg headroom or loads serialize;
// (R5) serial fold depth >> launch overhead; (R7) VALUBusy 5% = the kernel was
// pure latency: serial path loads + post-barrier-cold scattered B reads.

#define D 8
#define LPATH 1024
#define LASTROW 1023
#define BATCH 32
#define CHUNKS 32
#define MSTEP 32
#define SIG_STRIDE 4680
#define OFF2 8
#define OFF3 72
#define OFF4 584
#define NBLOCKS 256
#define FLAGS_BYTE_OFF (32u << 20)  // flags 32 MiB into ws (sig data: 19.2 MB)

// padded LDS sig tile
#define L3P 12                       // S3 row stride (8 data + 4 pad)
#define L4P 68                       // S4 lane-row stride (64 data + 4 pad)
#define LOFF3 72
#define LOFF4 (72 + 64 * L3P)        // 840
#define SIG_LDS (LOFF4 + 64 * L4P)   // 5192 floats
#define NF4 (SIG_STRIDE / 4)         // 1170 float4s per sig

__device__ __forceinline__ void store8(float* __restrict__ p, const float* src) {
  *(float4*)p       = make_float4(src[0], src[1], src[2], src[3]);
  *(float4*)(p + 4) = make_float4(src[4], src[5], src[6], src[7]);
}

// flat sig float index -> padded LDS offset (float4-safe: regions 4-aligned)
__device__ __forceinline__ int pad_off(int f) {
  if (f < OFF3) return f;
  if (f < OFF4) { int r = (f - OFF3) >> 3; return LOFF3 + r * L3P + ((f - OFF3) & 7); }
  int r = (f - OFF4) >> 6;
  return LOFF4 + r * L4P + ((f - OFF4) & 63);
}

__device__ __forceinline__ void stage_read(const float* __restrict__ g,
                                           float4 sv[5], int tid) {
#pragma unroll
  for (int it = 0; it < 5; ++it) {
    int n = tid + it * 256;
    if (n < NF4) sv[it] = *(const float4*)(g + 4 * n);
  }
}

__device__ __forceinline__ void stage_write(float* __restrict__ S,
                                            const float4 sv[5], int tid) {
#pragma unroll
  for (int it = 0; it < 5; ++it) {
    int n = tid + it * 256;
    if (n < NF4) *(float4*)(S + pad_off(4 * n)) = sv[it];
  }
}

// Grid barrier: 256 blocks co-resident by construction. Release publishes via
// L2 writeback; acquire invalidates before consuming cross-XCD data.
__device__ __forceinline__ void grid_barrier(unsigned int* flag) {
  __syncthreads();
  if (threadIdx.x == 0) {
    __hip_atomic_fetch_add(flag, 1u, __ATOMIC_RELEASE, __HIP_MEMORY_SCOPE_AGENT);
    while (__hip_atomic_load(flag, __ATOMIC_RELAXED, __HIP_MEMORY_SCOPE_AGENT) <
           (unsigned int)NBLOCKS) {
      __builtin_amdgcn_s_sleep(8);
    }
    (void)__hip_atomic_load(flag, __ATOMIC_ACQUIRE, __HIP_MEMORY_SCOPE_AGENT);
  }
  __syncthreads();
}

// k-sliced Chen fold from a padded LDS sig tile. Lane (i,j), slice k0=2q:
// s1=S1[i], s2=S2[i][j], s3[k]=S3[i][j][k] (full), s4[t][m]=S4[i][j][k0+t][m].
__device__ __forceinline__ void fold_lds(const float* __restrict__ S, float& s1,
                                         float& s2, float s3[D], float s4[2][D],
                                         int i, int j, int lane, int k0) {
  float b1i = S[i];
  float b1j = S[j];
  float sb1[D];
#pragma unroll
  for (int m = 0; m < D; ++m) sb1[m] = S[m];
  float b2own = S[OFF2 + lane];
  float b2row[D], b3own[D];
  *(float4*)&b2row[0] = *(const float4*)&S[OFF2 + j * 8];
  *(float4*)&b2row[4] = *(const float4*)&S[OFF2 + j * 8 + 4];
  *(float4*)&b3own[0] = *(const float4*)&S[LOFF3 + lane * L3P];
  *(float4*)&b3own[4] = *(const float4*)&S[LOFF3 + lane * L3P + 4];

  // C4 = A4 + B4 + A3[i,j,k]B1[m] + A2[i,j]B2[k,m] + A1[i]B3[j,k,m]
#pragma unroll
  for (int t = 0; t < 2; ++t) {
    const int k = k0 + t;
    float b2k[D], b3k[D], b4[D];
    *(float4*)&b2k[0] = *(const float4*)&S[OFF2 + k * 8];
    *(float4*)&b2k[4] = *(const float4*)&S[OFF2 + k * 8 + 4];
    *(float4*)&b3k[0] = *(const float4*)&S[LOFF3 + (j * 8 + k) * L3P];
    *(float4*)&b3k[4] = *(const float4*)&S[LOFF3 + (j * 8 + k) * L3P + 4];
    *(float4*)&b4[0]  = *(const float4*)&S[LOFF4 + lane * L4P + k * 8];
    *(float4*)&b4[4]  = *(const float4*)&S[LOFF4 + lane * L4P + k * 8 + 4];
    float a3k = s3[k];
#pragma unroll
    for (int m = 0; m < D; ++m) {
      float v = __builtin_fmaf(a3k, sb1[m], s4[t][m] + b4[m]);
      v = __builtin_fmaf(s2, b2k[m], v);
      s4[t][m] = __builtin_fmaf(s1, b3k[m], v);
    }
  }
  // C3 = A3 + B3 + A1[i]B2[j,k] + A2[i,j]B1[k]
#pragma unroll
  for (int k = 0; k < D; ++k) {
    float v = __builtin_fmaf(s1, b2row[k], s3[k] + b3own[k]);
    s3[k] = __builtin_fmaf(s2, sb1[k], v);
  }
  s2 = s2 + b2own + s1 * b1j;
  s1 = s1 + b1i;
}

// Stage sig0 -> init state; then fold sigs 1..nsig-1 with LDS double-buffer:
// next sig's global loads are issued before the current fold's VALU.
__device__ __forceinline__ void run_staged_folds(
    const float* __restrict__ gbase, int stride, int nsig,
    float (*lds)[SIG_LDS], int tid, int i, int j, int lane, int k0, float& s1,
    float& s2, float s3[D], float s4[2][D]) {
  {
    float4 sv[5];
    stage_read(gbase, sv, tid);
    stage_write(lds[0], sv, tid);
  }
  __syncthreads();
  {
    float4 sv[5];
    stage_read(gbase + (size_t)stride * SIG_STRIDE, sv, tid);  // sig1 in flight
    const float* __restrict__ S = lds[0];
    s1 = S[i];
    s2 = S[OFF2 + lane];
    *(float4*)&s3[0] = *(const float4*)&S[LOFF3 + lane * L3P];
    *(float4*)&s3[4] = *(const float4*)&S[LOFF3 + lane * L3P + 4];
#pragma unroll
    for (int t = 0; t < 2; ++t) {
      *(float4*)&s4[t][0] = *(const float4*)&S[LOFF4 + lane * L4P + (k0 + t) * 8];
      *(float4*)&s4[t][4] = *(const float4*)&S[LOFF4 + lane * L4P + (k0 + t) * 8 + 4];
    }
    stage_write(lds[1], sv, tid);
  }
  __syncthreads();
#pragma unroll 1
  for (int c = 1; c < nsig; ++c) {
    float4 sv[5];
    if (c + 1 < nsig)
      stage_read(gbase + (size_t)(c + 1) * stride * SIG_STRIDE, sv, tid);
    fold_lds(lds[c & 1], s1, s2, s3, s4, i, j, lane, k0);
    if (c + 1 < nsig) stage_write(lds[(c + 1) & 1], sv, tid);
    __syncthreads();
  }
}

__global__ __launch_bounds__(256, 1) void sig_fused(const float* __restrict__ path,
                                                    float* __restrict__ ws,
                                                    float* __restrict__ out,
                                                    unsigned int* __restrict__ flags) {
  __shared__ float lds_path[129 * D];      // 4.1 KB
  __shared__ float lds_sig[2][SIG_LDS];    // 41.5 KB

  const int tid  = threadIdx.x;
  const int wv   = tid >> 6;               // wave in block 0..3
  const int lane = tid & 63;
  const int gw   = blockIdx.x * 4 + wv;    // 0..1023
  const int i = lane >> 3;
  const int j = lane & 7;

  // ---------------- Phase A: per-chunk signature, path staged via LDS -------
  {
    const int bb = gw >> 5;
    const int c  = gw & (CHUNKS - 1);
    const int c0 = (blockIdx.x * 4) & (CHUNKS - 1);  // block's first chunk
    const int row0 = c0 * MSTEP;
    const float* __restrict__ bp = path + (size_t)bb * (LPATH * D);

    const int nrows = (129 < LPATH - row0) ? 129 : (LPATH - row0);
    const int nf4p = nrows * 2;
#pragma unroll
    for (int it = 0; it < 2; ++it) {
      int n = tid + it * 256;
      if (n < nf4p)
        *(float4*)&lds_path[4 * n] = *(const float4*)(bp + (size_t)row0 * D + 4 * n);
    }
    __syncthreads();

    const int rbase = (c - c0) * MSTEP;  // relative row of chunk start
    float cm[D];
    *(float4*)&cm[0] = *(const float4*)&lds_path[rbase * D];
    *(float4*)&cm[4] = *(const float4*)&lds_path[rbase * D + 4];
    float cwi = lds_path[rbase * D + i];
    float cwj = lds_path[rbase * D + j];

    float s1 = 0.f, s2 = 0.f;
    float s3[D] = {0.f, 0.f, 0.f, 0.f, 0.f, 0.f, 0.f, 0.f};
    float s4[D][D];
#pragma unroll
    for (int k = 0; k < D; ++k)
#pragma unroll
      for (int m = 0; m < D; ++m) s4[k][m] = 0.f;

#pragma unroll 2
    for (int t = 0; t < MSTEP; ++t) {
      int grow = c * MSTEP + t + 1;
      grow = grow > LASTROW ? LASTROW : grow;  // clamp -> zero-inc pad
      const int r = grow - row0;
      float nm[D];
      *(float4*)&nm[0] = *(const float4*)&lds_path[r * D];
      *(float4*)&nm[4] = *(const float4*)&lds_path[r * D + 4];
      float nwi = lds_path[r * D + i];
      float nwj = lds_path[r * D + j];

      float wm[D];
#pragma unroll
      for (int m = 0; m < D; ++m) wm[m] = nm[m] - cm[m];
      float wi = nwi - cwi, wj = nwj - cwj;

      // level 4: S4 += S3(x)w + S2(x)w^2/2 + S1(x)w^3/6 + w^4/24 (Horner)
      float h1  = __builtin_fmaf(wi, 0.25f, s1);
      float h2  = __builtin_fmaf(h1, wj * (1.f / 3.f), s2);
      float hb2 = h2 * 0.5f;
      float b3[D];
#pragma unroll
      for (int k = 0; k < D; ++k) b3[k] = __builtin_fmaf(hb2, wm[k], s3[k]);
#pragma unroll
      for (int k = 0; k < D; ++k)
#pragma unroll
        for (int m = 0; m < D; ++m)
          s4[k][m] = __builtin_fmaf(b3[k], wm[m], s4[k][m]);

      // level 3
      float c1 = __builtin_fmaf(wi, (1.f / 3.f), s1);
      float c2 = __builtin_fmaf(c1, wj * 0.5f, s2);
#pragma unroll
      for (int k = 0; k < D; ++k) s3[k] = __builtin_fmaf(c2, wm[k], s3[k]);

      // levels 2, 1
      float d1 = __builtin_fmaf(wi, 0.5f, s1);
      s2 = __builtin_fmaf(d1, wj, s2);
      s1 += wi;

#pragma unroll
      for (int m = 0; m < D; ++m) cm[m] = nm[m];
      cwi = nwi; cwj = nwj;
    }

    float* __restrict__ slot = ws + (size_t)(bb * CHUNKS + c) * SIG_STRIDE;
    if (j == 0) slot[i] = s1;
    slot[OFF2 + lane] = s2;
    store8(slot + OFF3 + lane * 8, s3);
#pragma unroll
    for (int k = 0; k < D; ++k) store8(slot + OFF4 + lane * 64 + k * 8, s4[k]);
  }

  grid_barrier(&flags[0]);

  // ---------------- Phase B: blocks 0..127, one (batch,group) each ----------
  if (blockIdx.x < 128) {
    const int bb = blockIdx.x >> 2;
    const int g  = blockIdx.x & 3;
    const int q  = wv;
    const int k0 = q * 2;
    float* __restrict__ base = ws + (size_t)(bb * CHUNKS + g * 8) * SIG_STRIDE;

    float s1, s2, s3[D], s4[2][D];
    run_staged_folds(base, 1, 8, lds_sig, tid, i, j, lane, k0, s1, s2, s3, s4);

    store8(base + OFF4 + lane * 64 + k0 * 8, s4[0]);
    store8(base + OFF4 + lane * 64 + (k0 + 1) * 8, s4[1]);
    if (q == 0) {
      if (j == 0) base[i] = s1;
      base[OFF2 + lane] = s2;
      store8(base + OFF3 + lane * 8, s3);
    }
  }

  grid_barrier(&flags[1]);

  // ---------------- Phase C: blocks 0..31, fold the 4 partials -> out -------
  if (blockIdx.x < 32) {
    const int bb = blockIdx.x;
    const int q  = wv;
    const int k0 = q * 2;
    const float* __restrict__ base = ws + (size_t)bb * CHUNKS * SIG_STRIDE;

    float s1, s2, s3[D], s4[2][D];
    run_staged_folds(base, 8, 4, lds_sig, tid, i, j, lane, k0, s1, s2, s3, s4);

    // d_out: S1 (32x8) | S2 (32x64) | S3 (32x512) | S4 (32x4096)
    if (q == 0) {
      if (j == 0) out[bb * 8 + i] = s1;
      out[256 + bb * 64 + lane] = s2;
      store8(out + 2304 + bb * 512 + lane * 8, s3);
    }
    store8(out + 18688 + bb * 4096 + lane * 64 + k0 * 8, s4[0]);
    store8(out + 18688 + bb * 4096 + lane * 64 + (k0 + 1) * 8, s4[1]);
  }
}

extern "C" void kernel_launch(void* const* d_in, const int* in_sizes, int n_in,
                              void* d_out, int out_size, void* d_ws, size_t ws_size,
                              hipStream_t stream) {
  const float* path = (const float*)d_in[0];
  // d_in[1] = depth (==4), compile-time specialized.
  float* out = (float*)d_out;
  float* ws  = (float*)d_ws;  // sig data: first 19.2 MB; flags at +32 MiB
  unsigned int* flags = (unsigned int*)((char*)d_ws + FLAGS_BYTE_OFF);

  hipMemsetAsync(flags, 0, 2 * sizeof(unsigned int), stream);
  sig_fused<<<dim3(NBLOCKS), dim3(256), 0, stream>>>(path, ws, out, flags);
}

// Round 9
// 100.717 us; speedup vs baseline: 1.5557x; 1.5557x over previous
//
#include <hip/hip_runtime.h>

// Path signature, depth 4: B=32, L=1024, d=8, fp32.
// Levels: S1(8) S2(64) S3(512) S4(4096); sig stride 4680 floats.
//
// R9 = R4 topology (best measured, 107.5us) + latency-fixed fold kernels.
//  sig_chunk: 4 k-slice waves per 32-inc chunk (4096 waves) - R4 verbatim.
//  sig_fold8: 128 blocks; block (bb,g) folds chunk sigs [8g..8g+8) of batch
//    bb; 4 q-waves k-slice S4. Levels 1-3 of the next B-sig staged in a tiny
//    2.3KB double-buffered LDS tile (1 float4/thread); the B4 k-slice (no
//    cross-wave reuse) prefetched into 16 VGPRs. One sync per fold.
//  sig_fold4: 32 blocks, same machinery over the 4 partials, writes d_out.
// Lessons: (R2) never unroll fold loops (VGPR-cap spill); (R3) waves need reg
// headroom or loads serialize; (R5) serial depth >> launch overhead; (R7/R8)
// the compiler sinks big register prefetch buffers (and collapses VGPR alloc),
// so prefetch state must be SMALL (<=24 regs) to survive; (R8) LDS padding of
// +4 floats makes stride=4 mod 32 = 8-way conflicts - stage raw, keep reused
// broadcast data (levels 1-3) in LDS and private data (B4) in registers.

#define D 8
#define LPATH 1024
#define NINC 1023
#define BATCH 32
#define CHUNKS 32
#define MSTEP 32
#define SIG_STRIDE 4680
#define OFF2 8
#define OFF3 72
#define OFF4 584
#define N13F4 146  // 584 floats of levels 1-3 = 146 float4s

__device__ __forceinline__ float readlane_f(float v, int l) {
  return __builtin_bit_cast(float, __builtin_amdgcn_readlane(__builtin_bit_cast(int, v), l));
}

__device__ __forceinline__ void load8(const float* __restrict__ p, float* dst) {
  float4 lo = *(const float4*)p;
  float4 hi = *(const float4*)(p + 4);
  dst[0] = lo.x; dst[1] = lo.y; dst[2] = lo.z; dst[3] = lo.w;
  dst[4] = hi.x; dst[5] = hi.y; dst[6] = hi.z; dst[7] = hi.w;
}

__device__ __forceinline__ void store8(float* __restrict__ p, const float* src) {
  *(float4*)p       = make_float4(src[0], src[1], src[2], src[3]);
  *(float4*)(p + 4) = make_float4(src[4], src[5], src[6], src[7]);
}

// ------ Kernel 1: per-chunk signature, 4 waves per chunk (k-sliced) --------
// (R4 verbatim - it passed and was fast enough to hide under the 44us fills.)
__global__ __launch_bounds__(256) void sig_chunk(const float* __restrict__ path,
                                                 float* __restrict__ ws) {
  const int gw   = (blockIdx.x * 256 + threadIdx.x) >> 6;  // 0..4095
  const int lane = threadIdx.x & 63;
  const int q = gw & 3;
  const int c = (gw >> 2) & (CHUNKS - 1);
  const int b = gw >> 7;
  const int i = lane >> 3;
  const int j = lane & 7;
  const int k0 = q * 2;

  const float* __restrict__ pj = path + (size_t)b * (LPATH * D) + j;
  const int g0 = c * MSTEP;

  float pc = pj[g0 * D];
  int nx = g0 + 1; nx = nx > NINC ? NINC : nx;
  float pnext = pj[nx * D];

  float s1 = 0.f, s2 = 0.f;
  float s3[D] = {0.f, 0.f, 0.f, 0.f, 0.f, 0.f, 0.f, 0.f};
  float s4[2][D];
#pragma unroll
  for (int t = 0; t < 2; ++t)
#pragma unroll
    for (int m = 0; m < D; ++m) s4[t][m] = 0.f;

#pragma unroll 1
  for (int t = 0; t < MSTEP; ++t) {
    float pn = pnext;
    int n2 = g0 + t + 2; n2 = n2 > NINC ? NINC : n2;  // clamp -> zero-inc pad
    pnext = pj[n2 * D];

    float wj = pn - pc;
    pc = pn;
    float wi = __shfl(wj, i, 64);
    float wm[D];
#pragma unroll
    for (int m = 0; m < D; ++m) wm[m] = readlane_f(wj, m);

    // level-4 slice: S4 += S3(x)w + S2(x)w^2/2 + S1(x)w^3/6 + w^4/24 (Horner)
    float h1  = __builtin_fmaf(wi, 0.25f, s1);
    float h2  = __builtin_fmaf(h1, wj * (1.f / 3.f), s2);
    float hb2 = h2 * 0.5f;
    float b3a = __builtin_fmaf(hb2, wm[k0], s3[k0]);
    float b3b = __builtin_fmaf(hb2, wm[k0 + 1], s3[k0 + 1]);
#pragma unroll
    for (int m = 0; m < D; ++m) s4[0][m] = __builtin_fmaf(b3a, wm[m], s4[0][m]);
#pragma unroll
    for (int m = 0; m < D; ++m) s4[1][m] = __builtin_fmaf(b3b, wm[m], s4[1][m]);

    // level 3 (full, replicated across q-waves)
    float c1 = __builtin_fmaf(wi, (1.f / 3.f), s1);
    float c2 = __builtin_fmaf(c1, wj * 0.5f, s2);
#pragma unroll
    for (int k = 0; k < D; ++k) s3[k] = __builtin_fmaf(c2, wm[k], s3[k]);

    // levels 2, 1
    float d1 = __builtin_fmaf(wi, 0.5f, s1);
    s2 = __builtin_fmaf(d1, wj, s2);
    s1 += wi;
  }

  float* __restrict__ slot = ws + (size_t)(b * CHUNKS + c) * SIG_STRIDE;
  store8(slot + OFF4 + lane * 64 + k0 * 8, s4[0]);
  store8(slot + OFF4 + lane * 64 + (k0 + 1) * 8, s4[1]);
  if (q == 0) {
    if (j == 0) slot[i] = s1;
    slot[OFF2 + lane] = s2;
    store8(slot + OFF3 + lane * 8, s3);
  }
}

// ---- fold from LDS levels1-3 + register B4 slice (k-sliced Chen product) ---
// Lane (i,j), slice k0: s1=S1[i], s2=S2[i][j], s3[k]=S3[i][j][k] full,
// s4[t][m]=S4[i][j][k0+t][m]. L = flat {S1|S2|S3} tile (584 floats).
__device__ __forceinline__ void fold_lds(const float* __restrict__ L,
                                         const float b4[2][D], float& s1,
                                         float& s2, float s3[D], float s4[2][D],
                                         int i, int j, int lane, int k0) {
  float b1i = L[i];
  float b1j = L[j];
  float sb1[D];
#pragma unroll
  for (int m = 0; m < D; ++m) sb1[m] = L[m];
  float b2own = L[OFF2 + lane];
  float b2row[D], b3own[D];
  *(float4*)&b2row[0] = *(const float4*)&L[OFF2 + j * 8];
  *(float4*)&b2row[4] = *(const float4*)&L[OFF2 + j * 8 + 4];
  *(float4*)&b3own[0] = *(const float4*)&L[OFF3 + lane * 8];
  *(float4*)&b3own[4] = *(const float4*)&L[OFF3 + lane * 8 + 4];

  // C4 = A4 + B4 + A3[i,j,k]B1[m] + A2[i,j]B2[k,m] + A1[i]B3[j,k,m]
#pragma unroll
  for (int t = 0; t < 2; ++t) {
    const int k = k0 + t;
    float b2k[D], b3k[D];
    *(float4*)&b2k[0] = *(const float4*)&L[OFF2 + k * 8];
    *(float4*)&b2k[4] = *(const float4*)&L[OFF2 + k * 8 + 4];
    *(float4*)&b3k[0] = *(const float4*)&L[OFF3 + (j * 8 + k) * 8];
    *(float4*)&b3k[4] = *(const float4*)&L[OFF3 + (j * 8 + k) * 8 + 4];
    float a3k = s3[k];
#pragma unroll
    for (int m = 0; m < D; ++m) {
      float v = __builtin_fmaf(a3k, sb1[m], s4[t][m] + b4[t][m]);
      v = __builtin_fmaf(s2, b2k[m], v);
      s4[t][m] = __builtin_fmaf(s1, b3k[m], v);
    }
  }
  // C3 = A3 + B3 + A1[i]B2[j,k] + A2[i,j]B1[k]
#pragma unroll
  for (int k = 0; k < D; ++k) {
    float v = __builtin_fmaf(s1, b2row[k], s3[k] + b3own[k]);
    s3[k] = __builtin_fmaf(s2, sb1[k], v);
  }
  s2 = s2 + b2own + s1 * b1j;
  s1 = s1 + b1i;
}

// Shared fold pipeline: init state from sig0 at base, fold sigs 1..nsig-1
// (stride slots apart). lds13: 2 x 584-float tiles. One sync per fold.
__device__ __forceinline__ void staged_folds(float* __restrict__ base, int stride,
                                             int nsig, float (*lds13)[592],
                                             int tid, int i, int j, int lane,
                                             int k0, float& s1, float& s2,
                                             float s3[D], float s4[2][D]) {
  // state <- sig 0
  s1 = base[i];
  s2 = base[OFF2 + lane];
  load8(base + OFF3 + lane * 8, s3);
  load8(base + OFF4 + lane * 64 + k0 * 8, s4[0]);
  load8(base + OFF4 + lane * 64 + (k0 + 1) * 8, s4[1]);

  // prologue: stage sig1 levels1-3 -> lds13[1]; prefetch sig1's B4 slice
  const float* __restrict__ B1p = base + (size_t)stride * SIG_STRIDE;
  float b4cur[2][D];
  load8(B1p + OFF4 + lane * 64 + k0 * 8, b4cur[0]);
  load8(B1p + OFF4 + lane * 64 + (k0 + 1) * 8, b4cur[1]);
  if (tid < N13F4) {
    float4 sv = *(const float4*)(B1p + tid * 4);
    *(float4*)&lds13[1][tid * 4] = sv;
  }
  __syncthreads();

#pragma unroll 1
  for (int c = 1; c < nsig; ++c) {
    const bool more = (c + 1 < nsig);
    const float* __restrict__ Bn = base + (size_t)(c + 1) * stride * SIG_STRIDE;
    float4 svn;
    float b4n[2][D];
    if (more) {
      if (tid < N13F4) svn = *(const float4*)(Bn + tid * 4);
      load8(Bn + OFF4 + lane * 64 + k0 * 8, b4n[0]);
      load8(Bn + OFF4 + lane * 64 + (k0 + 1) * 8, b4n[1]);
    }

    fold_lds(lds13[c & 1], b4cur, s1, s2, s3, s4, i, j, lane, k0);

    if (more) {
      if (tid < N13F4) *(float4*)&lds13[(c + 1) & 1][tid * 4] = svn;
#pragma unroll
      for (int t = 0; t < 2; ++t)
#pragma unroll
        for (int m = 0; m < D; ++m) b4cur[t][m] = b4n[t][m];
    }
    __syncthreads();
  }
}

// ------ Kernel 2: block (bb,g) folds 8 chunk sigs -> partial in slot 8g -----
__global__ __launch_bounds__(256) void sig_fold8(float* __restrict__ ws) {
  __shared__ alignas(16) float lds13[2][592];
  const int tid  = threadIdx.x;
  const int q    = tid >> 6;  // k-slice wave 0..3
  const int lane = tid & 63;
  const int bb = blockIdx.x >> 2;
  const int g  = blockIdx.x & 3;
  const int i = lane >> 3;
  const int j = lane & 7;
  const int k0 = q * 2;

  float* __restrict__ base = ws + (size_t)(bb * CHUNKS + g * 8) * SIG_STRIDE;

  float s1, s2, s3[D], s4[2][D];
  staged_folds(base, 1, 8, lds13, tid, i, j, lane, k0, s1, s2, s3, s4);

  store8(base + OFF4 + lane * 64 + k0 * 8, s4[0]);
  store8(base + OFF4 + lane * 64 + (k0 + 1) * 8, s4[1]);
  if (q == 0) {
    if (j == 0) base[i] = s1;
    base[OFF2 + lane] = s2;
    store8(base + OFF3 + lane * 8, s3);
  }
}

// ------ Kernel 3: block bb folds the 4 partials of batch bb -> d_out --------
__global__ __launch_bounds__(256) void sig_fold4(float* __restrict__ ws,
                                                 float* __restrict__ out) {
  __shared__ alignas(16) float lds13[2][592];
  const int tid  = threadIdx.x;
  const int q    = tid >> 6;
  const int lane = tid & 63;
  const int bb = blockIdx.x;
  const int i = lane >> 3;
  const int j = lane & 7;
  const int k0 = q * 2;

  float* __restrict__ base = ws + (size_t)bb * CHUNKS * SIG_STRIDE;

  float s1, s2, s3[D], s4[2][D];
  staged_folds(base, 8, 4, lds13, tid, i, j, lane, k0, s1, s2, s3, s4);

  // d_out: S1 (32x8) | S2 (32x64) | S3 (32x512) | S4 (32x4096)
  if (q == 0) {
    if (j == 0) out[bb * 8 + i] = s1;
    out[256 + bb * 64 + lane] = s2;
    store8(out + 2304 + bb * 512 + lane * 8, s3);
  }
  store8(out + 18688 + bb * 4096 + lane * 64 + k0 * 8, s4[0]);
  store8(out + 18688 + bb * 4096 + lane * 64 + (k0 + 1) * 8, s4[1]);
}

extern "C" void kernel_launch(void* const* d_in, const int* in_sizes, int n_in,
                              void* d_out, int out_size, void* d_ws, size_t ws_size,
                              hipStream_t stream) {
  const float* path = (const float*)d_in[0];
  // d_in[1] = depth (==4), compile-time specialized.
  float* out = (float*)d_out;
  float* ws  = (float*)d_ws;  // 32*32*4680*4 = 19.2 MB used

  // 32 batches x 32 chunks x 4 k-slice waves = 4096 waves = 1024 blocks
  sig_chunk<<<dim3(1024), dim3(256), 0, stream>>>(path, ws);
  // 32 batches x 4 groups = 128 blocks (4 q-waves each)
  sig_fold8<<<dim3(128), dim3(256), 0, stream>>>(ws);
  // 32 batches = 32 blocks
  sig_fold4<<<dim3(32), dim3(256), 0, stream>>>(ws, out);
}

// Round 10
// 97.191 us; speedup vs baseline: 1.6121x; 1.0363x over previous
//
#include <hip/hip_runtime.h>

// Path signature, depth 4: B=32, L=1024, d=8, fp32.
// Levels: S1(8) S2(64) S3(512) S4(4096); sig stride 4680 floats.
//
// R10 = R9 (best, 100.7us) + LDS-staged path in sig_chunk.
//  sig_chunk: one block per chunk (4 k-slice q-waves). Block stages its 33
//    path rows (1.05 KB) into LDS with one coalesced float4 load/thread, then
//    each step reads the next row via broadcast ds_read (conflict-free) -
//    kills the 32-long serial chain of ~800cyc cold scalar loads that made
//    chunk ~12us. No shfl/readlane needed (row vector is in registers).
//  sig_fold8: 128 blocks; levels1-3 of next B-sig double-buffered in 2.3KB
//    LDS (1 float4/thread), B4 k-slice prefetched in 16 VGPRs. R9 verbatim.
//  sig_fold4: 32 blocks, same machinery, writes d_out. R9 verbatim.
// Lessons: (R2) never unroll fold loops (VGPR-cap spill); (R3) reg headroom
// or loads serialize; (R5) serial depth >> launch overhead; (R7/R8) compiler
// sinks big register prefetch buffers - keep prefetch state small; (R8) +4
// LDS padding = 8-way conflicts - stage raw; (R9) harness floor ~53us
// (256MiB poison fill + restore), kernels sum ~47us.

#define D 8
#define LPATH 1024
#define NINC 1023
#define BATCH 32
#define CHUNKS 32
#define MSTEP 32
#define SIG_STRIDE 4680
#define OFF2 8
#define OFF3 72
#define OFF4 584
#define N13F4 146  // 584 floats of levels 1-3 = 146 float4s

__device__ __forceinline__ void load8(const float* __restrict__ p, float* dst) {
  float4 lo = *(const float4*)p;
  float4 hi = *(const float4*)(p + 4);
  dst[0] = lo.x; dst[1] = lo.y; dst[2] = lo.z; dst[3] = lo.w;
  dst[4] = hi.x; dst[5] = hi.y; dst[6] = hi.z; dst[7] = hi.w;
}

__device__ __forceinline__ void store8(float* __restrict__ p, const float* src) {
  *(float4*)p       = make_float4(src[0], src[1], src[2], src[3]);
  *(float4*)(p + 4) = make_float4(src[4], src[5], src[6], src[7]);
}

// ------ Kernel 1: one block per chunk; path staged via LDS ------------------
__global__ __launch_bounds__(256) void sig_chunk(const float* __restrict__ path,
                                                 float* __restrict__ ws) {
  __shared__ alignas(16) float lp[33 * D];  // 1.05 KB

  const int tid  = threadIdx.x;
  const int lane = tid & 63;
  const int q    = tid >> 6;               // k-slice wave 0..3
  const int b = blockIdx.x >> 5;           // batch
  const int c = blockIdx.x & (CHUNKS - 1); // chunk
  const int i = lane >> 3;
  const int j = lane & 7;
  const int k0 = q * 2;

  const int g0 = c * MSTEP;
  const int nrows = (33 < LPATH - g0) ? 33 : (LPATH - g0);
  const int nf4 = nrows * 2;
  const float* __restrict__ bp = path + (size_t)b * (LPATH * D) + (size_t)g0 * D;

  if (tid < nf4) *(float4*)&lp[4 * tid] = *(const float4*)(bp + 4 * tid);
  __syncthreads();

  // previous row in registers
  float cm[D];
  *(float4*)&cm[0] = *(const float4*)&lp[0];
  *(float4*)&cm[4] = *(const float4*)&lp[4];
  float cwi = lp[i], cwj = lp[j];

  float s1 = 0.f, s2 = 0.f;
  float s3[D] = {0.f, 0.f, 0.f, 0.f, 0.f, 0.f, 0.f, 0.f};
  float s4[2][D];
#pragma unroll
  for (int t = 0; t < 2; ++t)
#pragma unroll
    for (int m = 0; m < D; ++m) s4[t][m] = 0.f;

#pragma unroll 1
  for (int t = 0; t < MSTEP; ++t) {
    int rc = t + 1;
    rc = rc < nrows ? rc : nrows - 1;  // clamp -> zero-increment pad
    float nm[D];
    *(float4*)&nm[0] = *(const float4*)&lp[rc * D];      // broadcast read
    *(float4*)&nm[4] = *(const float4*)&lp[rc * D + 4];
    float nwi = lp[rc * D + i];                          // conflict-free bcast
    float nwj = lp[rc * D + j];

    float wm[D];
#pragma unroll
    for (int m = 0; m < D; ++m) wm[m] = nm[m] - cm[m];
    float wi = nwi - cwi, wj = nwj - cwj;

    // level-4 slice: S4 += S3(x)w + S2(x)w^2/2 + S1(x)w^3/6 + w^4/24 (Horner)
    float h1  = __builtin_fmaf(wi, 0.25f, s1);
    float h2  = __builtin_fmaf(h1, wj * (1.f / 3.f), s2);
    float hb2 = h2 * 0.5f;
    float b3a = __builtin_fmaf(hb2, wm[k0], s3[k0]);
    float b3b = __builtin_fmaf(hb2, wm[k0 + 1], s3[k0 + 1]);
#pragma unroll
    for (int m = 0; m < D; ++m) s4[0][m] = __builtin_fmaf(b3a, wm[m], s4[0][m]);
#pragma unroll
    for (int m = 0; m < D; ++m) s4[1][m] = __builtin_fmaf(b3b, wm[m], s4[1][m]);

    // level 3 (full, replicated across q-waves)
    float c1 = __builtin_fmaf(wi, (1.f / 3.f), s1);
    float c2 = __builtin_fmaf(c1, wj * 0.5f, s2);
#pragma unroll
    for (int k = 0; k < D; ++k) s3[k] = __builtin_fmaf(c2, wm[k], s3[k]);

    // levels 2, 1
    float d1 = __builtin_fmaf(wi, 0.5f, s1);
    s2 = __builtin_fmaf(d1, wj, s2);
    s1 += wi;

#pragma unroll
    for (int m = 0; m < D; ++m) cm[m] = nm[m];
    cwi = nwi; cwj = nwj;
  }

  float* __restrict__ slot = ws + (size_t)(b * CHUNKS + c) * SIG_STRIDE;
  store8(slot + OFF4 + lane * 64 + k0 * 8, s4[0]);
  store8(slot + OFF4 + lane * 64 + (k0 + 1) * 8, s4[1]);
  if (q == 0) {
    if (j == 0) slot[i] = s1;
    slot[OFF2 + lane] = s2;
    store8(slot + OFF3 + lane * 8, s3);
  }
}

// ---- fold from LDS levels1-3 + register B4 slice (k-sliced Chen product) ---
// Lane (i,j), slice k0: s1=S1[i], s2=S2[i][j], s3[k]=S3[i][j][k] full,
// s4[t][m]=S4[i][j][k0+t][m]. L = flat {S1|S2|S3} tile (584 floats).
__device__ __forceinline__ void fold_lds(const float* __restrict__ L,
                                         const float b4[2][D], float& s1,
                                         float& s2, float s3[D], float s4[2][D],
                                         int i, int j, int lane, int k0) {
  float b1i = L[i];
  float b1j = L[j];
  float sb1[D];
#pragma unroll
  for (int m = 0; m < D; ++m) sb1[m] = L[m];
  float b2own = L[OFF2 + lane];
  float b2row[D], b3own[D];
  *(float4*)&b2row[0] = *(const float4*)&L[OFF2 + j * 8];
  *(float4*)&b2row[4] = *(const float4*)&L[OFF2 + j * 8 + 4];
  *(float4*)&b3own[0] = *(const float4*)&L[OFF3 + lane * 8];
  *(float4*)&b3own[4] = *(const float4*)&L[OFF3 + lane * 8 + 4];

  // C4 = A4 + B4 + A3[i,j,k]B1[m] + A2[i,j]B2[k,m] + A1[i]B3[j,k,m]
#pragma unroll
  for (int t = 0; t < 2; ++t) {
    const int k = k0 + t;
    float b2k[D], b3k[D];
    *(float4*)&b2k[0] = *(const float4*)&L[OFF2 + k * 8];
    *(float4*)&b2k[4] = *(const float4*)&L[OFF2 + k * 8 + 4];
    *(float4*)&b3k[0] = *(const float4*)&L[OFF3 + (j * 8 + k) * 8];
    *(float4*)&b3k[4] = *(const float4*)&L[OFF3 + (j * 8 + k) * 8 + 4];
    float a3k = s3[k];
#pragma unroll
    for (int m = 0; m < D; ++m) {
      float v = __builtin_fmaf(a3k, sb1[m], s4[t][m] + b4[t][m]);
      v = __builtin_fmaf(s2, b2k[m], v);
      s4[t][m] = __builtin_fmaf(s1, b3k[m], v);
    }
  }
  // C3 = A3 + B3 + A1[i]B2[j,k] + A2[i,j]B1[k]
#pragma unroll
  for (int k = 0; k < D; ++k) {
    float v = __builtin_fmaf(s1, b2row[k], s3[k] + b3own[k]);
    s3[k] = __builtin_fmaf(s2, sb1[k], v);
  }
  s2 = s2 + b2own + s1 * b1j;
  s1 = s1 + b1i;
}

// Shared fold pipeline: init state from sig0 at base, fold sigs 1..nsig-1
// (stride slots apart). lds13: 2 x 584-float tiles. One sync per fold.
__device__ __forceinline__ void staged_folds(float* __restrict__ base, int stride,
                                             int nsig, float (*lds13)[592],
                                             int tid, int i, int j, int lane,
                                             int k0, float& s1, float& s2,
                                             float s3[D], float s4[2][D]) {
  // state <- sig 0
  s1 = base[i];
  s2 = base[OFF2 + lane];
  load8(base + OFF3 + lane * 8, s3);
  load8(base + OFF4 + lane * 64 + k0 * 8, s4[0]);
  load8(base + OFF4 + lane * 64 + (k0 + 1) * 8, s4[1]);

  // prologue: stage sig1 levels1-3 -> lds13[1]; prefetch sig1's B4 slice
  const float* __restrict__ B1p = base + (size_t)stride * SIG_STRIDE;
  float b4cur[2][D];
  load8(B1p + OFF4 + lane * 64 + k0 * 8, b4cur[0]);
  load8(B1p + OFF4 + lane * 64 + (k0 + 1) * 8, b4cur[1]);
  if (tid < N13F4) {
    float4 sv = *(const float4*)(B1p + tid * 4);
    *(float4*)&lds13[1][tid * 4] = sv;
  }
  __syncthreads();

#pragma unroll 1
  for (int c = 1; c < nsig; ++c) {
    const bool more = (c + 1 < nsig);
    const float* __restrict__ Bn = base + (size_t)(c + 1) * stride * SIG_STRIDE;
    float4 svn;
    float b4n[2][D];
    if (more) {
      if (tid < N13F4) svn = *(const float4*)(Bn + tid * 4);
      load8(Bn + OFF4 + lane * 64 + k0 * 8, b4n[0]);
      load8(Bn + OFF4 + lane * 64 + (k0 + 1) * 8, b4n[1]);
    }

    fold_lds(lds13[c & 1], b4cur, s1, s2, s3, s4, i, j, lane, k0);

    if (more) {
      if (tid < N13F4) *(float4*)&lds13[(c + 1) & 1][tid * 4] = svn;
#pragma unroll
      for (int t = 0; t < 2; ++t)
#pragma unroll
        for (int m = 0; m < D; ++m) b4cur[t][m] = b4n[t][m];
    }
    __syncthreads();
  }
}

// ------ Kernel 2: block (bb,g) folds 8 chunk sigs -> partial in slot 8g -----
__global__ __launch_bounds__(256) void sig_fold8(float* __restrict__ ws) {
  __shared__ alignas(16) float lds13[2][592];
  const int tid  = threadIdx.x;
  const int q    = tid >> 6;  // k-slice wave 0..3
  const int lane = tid & 63;
  const int bb = blockIdx.x >> 2;
  const int g  = blockIdx.x & 3;
  const int i = lane >> 3;
  const int j = lane & 7;
  const int k0 = q * 2;

  float* __restrict__ base = ws + (size_t)(bb * CHUNKS + g * 8) * SIG_STRIDE;

  float s1, s2, s3[D], s4[2][D];
  staged_folds(base, 1, 8, lds13, tid, i, j, lane, k0, s1, s2, s3, s4);

  store8(base + OFF4 + lane * 64 + k0 * 8, s4[0]);
  store8(base + OFF4 + lane * 64 + (k0 + 1) * 8, s4[1]);
  if (q == 0) {
    if (j == 0) base[i] = s1;
    base[OFF2 + lane] = s2;
    store8(base + OFF3 + lane * 8, s3);
  }
}

// ------ Kernel 3: block bb folds the 4 partials of batch bb -> d_out --------
__global__ __launch_bounds__(256) void sig_fold4(float* __restrict__ ws,
                                                 float* __restrict__ out) {
  __shared__ alignas(16) float lds13[2][592];
  const int tid  = threadIdx.x;
  const int q    = tid >> 6;
  const int lane = tid & 63;
  const int bb = blockIdx.x;
  const int i = lane >> 3;
  const int j = lane & 7;
  const int k0 = q * 2;

  float* __restrict__ base = ws + (size_t)bb * CHUNKS * SIG_STRIDE;

  float s1, s2, s3[D], s4[2][D];
  staged_folds(base, 8, 4, lds13, tid, i, j, lane, k0, s1, s2, s3, s4);

  // d_out: S1 (32x8) | S2 (32x64) | S3 (32x512) | S4 (32x4096)
  if (q == 0) {
    if (j == 0) out[bb * 8 + i] = s1;
    out[256 + bb * 64 + lane] = s2;
    store8(out + 2304 + bb * 512 + lane * 8, s3);
  }
  store8(out + 18688 + bb * 4096 + lane * 64 + k0 * 8, s4[0]);
  store8(out + 18688 + bb * 4096 + lane * 64 + (k0 + 1) * 8, s4[1]);
}

extern "C" void kernel_launch(void* const* d_in, const int* in_sizes, int n_in,
                              void* d_out, int out_size, void* d_ws, size_t ws_size,
                              hipStream_t stream) {
  const float* path = (const float*)d_in[0];
  // d_in[1] = depth (==4), compile-time specialized.
  float* out = (float*)d_out;
  float* ws  = (float*)d_ws;  // 32*32*4680*4 = 19.2 MB used

  // one block per chunk: 32 batches x 32 chunks = 1024 blocks (4 q-waves each)
  sig_chunk<<<dim3(1024), dim3(256), 0, stream>>>(path, ws);
  // 32 batches x 4 groups = 128 blocks
  sig_fold8<<<dim3(128), dim3(256), 0, stream>>>(ws);
  // 32 batches = 32 blocks
  sig_fold4<<<dim3(32), dim3(256), 0, stream>>>(ws, out);
}